// Round 6
// baseline (235.194 us; speedup 1.0000x reference)
//
#include <hip/hip_runtime.h>
#include <hip/hip_bf16.h>

// SimpleMetaConvKALN: x (64,64,64,64) f32, w (32,80,3,3) f32 -> out (64,128,64,64) f32
// y = conv3x3(aug(x), w) per group; instance-norm per (b,oc); silu.
// K reduced 80->64: the constant-1 channel block's contribution is analytic
// per (oc, edge-type) -> T[oc][3][3] added in epilogue.
// A = weights [tap][oc][k64] bf16 (double-buffered regs), B = aug LDS
// chunk-major [q][pix][8] -> D[oc][px] direct stores.

#define NB 64
#define NH 64
#define NW 64

typedef __attribute__((ext_vector_type(8)))  short bf16x8;
typedef __attribute__((ext_vector_type(16))) float f32x16;

__device__ __forceinline__ float silu(float v) {
    return v / (1.0f + __expf(-v));
}
__device__ __forceinline__ unsigned short tobf(float f) {  // RNE f32->bf16
    unsigned u = __float_as_uint(f);
    u += 0x7FFFu + ((u >> 16) & 1u);
    return (unsigned short)(u >> 16);
}

// ---- per-plane min/max (no atomics) ----
__global__ __launch_bounds__(256) void minmax_kernel(const float* __restrict__ x,
                                                     float* __restrict__ pmm) {
    int plane = blockIdx.x;          // b*64 + ch
    const float4* p = (const float4*)(x + (size_t)plane * 4096);
    int t = threadIdx.x;
    float mn = 3.4e38f, mx = -3.4e38f;
    #pragma unroll
    for (int k = 0; k < 4; ++k) {
        float4 v = p[t + k * 256];
        mn = fminf(mn, fminf(fminf(v.x, v.y), fminf(v.z, v.w)));
        mx = fmaxf(mx, fmaxf(fmaxf(v.x, v.y), fmaxf(v.z, v.w)));
    }
    #pragma unroll
    for (int off = 32; off; off >>= 1) {
        mn = fminf(mn, __shfl_xor(mn, off));
        mx = fmaxf(mx, __shfl_xor(mx, off));
    }
    __shared__ float smn[4], smx[4];
    int wid = t >> 6, lane = t & 63;
    if (lane == 0) { smn[wid] = mn; smx[wid] = mx; }
    __syncthreads();
    if (t == 0) {
        mn = fminf(fminf(smn[0], smn[1]), fminf(smn[2], smn[3]));
        mx = fmaxf(fmaxf(smx[0], smx[1]), fmaxf(smx[2], smx[3]));
        pmm[plane * 2]     = mn;
        pmm[plane * 2 + 1] = mx;
    }
}

// blk 0-3: reduce pmm -> wsf[g]; blk 4-75: repack w -> bf16 [tap][oc][k64];
// blk 76: ones-channel analytic table T[oc][ey][ex]
__global__ __launch_bounds__(256) void reduce_repack_kernel(const float* __restrict__ pmm,
                                                            const float* __restrict__ w,
                                                            float* __restrict__ wsf,
                                                            unsigned short* __restrict__ wpk,
                                                            float* __restrict__ Tt) {
    int blk = blockIdx.x;
    int t = threadIdx.x;
    if (blk < 4) {
        int g = blk;
        float mn = 3.4e38f, mx = -3.4e38f;
        #pragma unroll
        for (int j = 0; j < 4; ++j) {
            int p = t + j * 256;             // 0..1023
            int b = p >> 4, c = p & 15;
            int plane = b * 64 + g * 16 + c;
            mn = fminf(mn, pmm[plane * 2]);
            mx = fmaxf(mx, pmm[plane * 2 + 1]);
        }
        #pragma unroll
        for (int off = 32; off; off >>= 1) {
            mn = fminf(mn, __shfl_xor(mn, off));
            mx = fmaxf(mx, __shfl_xor(mx, off));
        }
        __shared__ float smn[4], smx[4];
        int wid = t >> 6, lane = t & 63;
        if (lane == 0) { smn[wid] = mn; smx[wid] = mx; }
        __syncthreads();
        if (t == 0) {
            mn = fminf(fminf(smn[0], smn[1]), fminf(smn[2], smn[3]));
            mx = fmaxf(fmaxf(smx[0], smx[1]), fmaxf(smx[2], smx[3]));
            wsf[g * 2]     = mn;
            wsf[g * 2 + 1] = mx;
        }
    } else if (blk < 76) {
        int idx = (blk - 4) * 256 + t;       // < 18432 = 9*32*64
        int tap = idx / 2048;
        int r = idx - tap * 2048;
        int oc = r >> 6;
        int k = r & 63;
        int orig = (k < 16) ? k : (k + 16);  // skip ones block (orig 16..31)
        wpk[idx] = tobf(w[oc * 720 + orig * 9 + tap]);
    } else {
        for (int i = t; i < 288; i += 256) {   // FIX: 288 entries, 256 threads
            int oc = i / 9, ty = i - oc * 9;
            int ey = ty / 3, ex = ty - ey * 3;
            int ky0 = (ey == 0) ? 1 : 0, ky1 = (ey == 2) ? 1 : 2;
            int kx0 = (ex == 0) ? 1 : 0, kx1 = (ex == 2) ? 1 : 2;
            float s = 0.f;
            for (int c = 0; c < 16; ++c)
                for (int ky = ky0; ky <= ky1; ++ky)
                    for (int kx = kx0; kx <= kx1; ++kx)
                        s += w[oc * 720 + (16 + c) * 9 + ky * 3 + kx];
            Tt[i] = s;
        }
    }
}

__global__ __launch_bounds__(512, 6) void conv_mfma_kernel(const float* __restrict__ x,
                                                           const float* __restrict__ wsf,
                                                           const unsigned short* __restrict__ wpk,
                                                           const float* __restrict__ Tt,
                                                           float* __restrict__ out) {
    // XCD swizzle: consecutive work-chunks of 512 land on one XCD
    int flat = blockIdx.x;                       // 0..4095
    int f = ((flat & 7) << 9) | (flat >> 3);     // bijective
    int tile = f & 15;
    int bg = f >> 4;
    int b = bg & 63;
    int g = bg >> 6;
    int th0 = (tile >> 2) * 16, tw0 = (tile & 3) * 16;

    // chunk-major: aug[q 0..7][pix 0..323][8 bf16]
    // q: 0=silu c0-7, 1=silu c8-15, 2=xn c0-7, 3=xn c8-15, 4=p2a, 5=p2b, 6=p3a, 7=p3b
    __shared__ unsigned short aug[8 * 324 * 8];   // 41472 B
    __shared__ float Tl[288];                     // +1152 B

    float xmin = wsf[g * 2];
    float xmax = wsf[g * 2 + 1];
    float inv = 2.0f / (xmax - xmin);

    const float* xg = x + ((size_t)b * 64 + g * 16) * 4096;
    int t = threadIdx.x;
    if (t < 288) Tl[t] = Tt[t];

    // ---- stage augmented tile (all LDS writes are b128) ----
    #pragma unroll
    for (int i = 0; i < 3; ++i) {
        int idx = t + i * 512;
        if (idx < 1296) {
            int kind = idx / 324;                // 0,1: silu ; 2,3: poly
            int pix = idx - kind * 324;
            int ly = pix / 18, lx = pix - ly * 18;
            int gh = th0 + ly - 1, gw = tw0 + lx - 1;
            bool ok = (gh >= 0 && gh < NH && gw >= 0 && gw < NW);
            const float* src = xg + gh * 64 + gw;
            if (kind < 2) {
                int c0 = kind * 8;
                bf16x8 v;
                #pragma unroll
                for (int j = 0; j < 8; ++j) {
                    float val = ok ? src[(size_t)(c0 + j) * 4096] : 0.f;
                    v[j] = (short)tobf(silu(val));
                }
                *(bf16x8*)&aug[(kind * 324 + pix) * 8] = v;
            } else {
                int half = kind & 1;
                int c0 = half * 8;
                bf16x8 v1, v2, v3;
                #pragma unroll
                for (int j = 0; j < 8; ++j) {
                    float val = ok ? src[(size_t)(c0 + j) * 4096] : 0.f;
                    float xn = (val - xmin) * inv - 1.f;
                    float p2 = 1.5f * xn * xn - 0.5f;
                    float p3 = (2.5f * xn * xn - 1.5f) * xn;
                    v1[j] = ok ? (short)tobf(xn) : (short)0;
                    v2[j] = ok ? (short)tobf(p2) : (short)0;
                    v3[j] = ok ? (short)tobf(p3) : (short)0;
                }
                *(bf16x8*)&aug[((2 + half) * 324 + pix) * 8] = v1;
                *(bf16x8*)&aug[((4 + half) * 324 + pix) * 8] = v2;
                *(bf16x8*)&aug[((6 + half) * 324 + pix) * 8] = v3;
            }
        }
    }
    __syncthreads();

    // ---- MFMA with per-tap double-buffered weight registers ----
    int wv = t >> 6;
    int lane = t & 63;
    int lo = lane & 31, hi = lane >> 5;
    int py = 2 * wv + (lo >> 4), px = lo & 15;   // B col = pixel

    const bf16x8* wp = (const bf16x8*)wpk;       // frag (tap,kcg,hi): (tap*32+oc)*8 + kcg*2 + hi

    f32x16 acc = {};
    bf16x8 W[2][4];
    #pragma unroll
    for (int kcg = 0; kcg < 4; ++kcg) W[0][kcg] = wp[lo * 8 + kcg * 2 + hi];

    #pragma unroll
    for (int tap = 0; tap < 9; ++tap) {
        const int cur = tap & 1, nxt = cur ^ 1;
        if (tap < 8) {
            #pragma unroll
            for (int kcg = 0; kcg < 4; ++kcg)
                W[nxt][kcg] = wp[((tap + 1) * 32 + lo) * 8 + kcg * 2 + hi];
        }
        const int ky = tap / 3, kx = tap % 3;
        const int hp = (py + ky) * 18 + (px + kx);
        #pragma unroll
        for (int kcg = 0; kcg < 4; ++kcg) {
            bf16x8 Bf = *(const bf16x8*)&aug[(((kcg * 2 + hi) * 324) + hp) * 8];
            acc = __builtin_amdgcn_mfma_f32_32x32x16_bf16(W[cur][kcg], Bf, acc, 0, 0, 0);
        }
    }

    // ---- epilogue: add analytic ones-channel term, direct coalesced stores ----
    int h = th0 + py, wc = tw0 + px;
    int ey = (h == 0) ? 0 : ((h == NH - 1) ? 2 : 1);
    int ex = (wc == 0) ? 0 : ((wc == NW - 1) ? 2 : 1);
    int et = ey * 3 + ex;
    size_t obase = ((size_t)b * 128 + g * 32) * 4096 + (size_t)h * 64 + wc;
    #pragma unroll
    for (int r = 0; r < 16; ++r) {
        int oc = (r & 3) + 8 * (r >> 2) + 4 * hi;
        out[obase + (size_t)oc * 4096] = acc[r] + Tl[oc * 9 + et];
    }
}

__global__ __launch_bounds__(256) void norm_kernel(float* __restrict__ out) {
    int plane = blockIdx.x;      // b*128 + ch
    float4* p = (float4*)(out + (size_t)plane * 4096);
    int t = threadIdx.x;
    float4 v[4];
    float s = 0.f, s2 = 0.f;
    #pragma unroll
    for (int k = 0; k < 4; ++k) {
        v[k] = p[t + k * 256];
        s  += v[k].x + v[k].y + v[k].z + v[k].w;
        s2 += v[k].x * v[k].x + v[k].y * v[k].y + v[k].z * v[k].z + v[k].w * v[k].w;
    }
    #pragma unroll
    for (int off = 32; off; off >>= 1) {
        s  += __shfl_xor(s, off);
        s2 += __shfl_xor(s2, off);
    }
    __shared__ float ss[4], ss2[4];
    int wid = t >> 6, lane = t & 63;
    if (lane == 0) { ss[wid] = s; ss2[wid] = s2; }
    __syncthreads();
    s  = ss[0] + ss[1] + ss[2] + ss[3];
    s2 = ss2[0] + ss2[1] + ss2[2] + ss2[3];
    float mean = s * (1.f / 4096.f);
    float var  = fmaxf(s2 * (1.f / 4096.f) - mean * mean, 0.f);
    float istd = rsqrtf(var + 1e-5f);
    #pragma unroll
    for (int k = 0; k < 4; ++k) {
        float4 o;
        o.x = (v[k].x - mean) * istd; o.x = silu(o.x);
        o.y = (v[k].y - mean) * istd; o.y = silu(o.y);
        o.z = (v[k].z - mean) * istd; o.z = silu(o.z);
        o.w = (v[k].w - mean) * istd; o.w = silu(o.w);
        p[t + k * 256] = o;
    }
}

extern "C" void kernel_launch(void* const* d_in, const int* in_sizes, int n_in,
                              void* d_out, int out_size, void* d_ws, size_t ws_size,
                              hipStream_t stream) {
    const float* x = (const float*)d_in[0];
    const float* w = (const float*)d_in[1];
    float* out = (float*)d_out;
    float* wsf = (float*)d_ws;                                        // 8 floats
    float* pmm = (float*)((char*)d_ws + 64);                          // 8192 floats
    unsigned short* wpk = (unsigned short*)((char*)d_ws + 64 + 32768);// 18432 bf16
    float* Tt = (float*)((char*)d_ws + 64 + 32768 + 36864);           // 288 floats

    hipLaunchKernelGGL(minmax_kernel, dim3(NB * 64), dim3(256), 0, stream, x, pmm);
    hipLaunchKernelGGL(reduce_repack_kernel, dim3(77), dim3(256), 0, stream, pmm, w, wsf, wpk, Tt);
    hipLaunchKernelGGL(conv_mfma_kernel, dim3(4096), dim3(512), 0, stream, x, wsf, wpk, Tt, out);
    hipLaunchKernelGGL(norm_kernel, dim3(NB * 128), dim3(256), 0, stream, out);
}

// Round 7
// 152.519 us; speedup vs baseline: 1.5421x; 1.5421x over previous
//
#include <hip/hip_runtime.h>
#include <hip/hip_bf16.h>

// SimpleMetaConvKALN: x (64,64,64,64) f32, w (32,80,3,3) f32 -> out (64,128,64,64) f32
// y = conv3x3(aug(x), w) per group; instance-norm per (b,oc); silu.
// K=64 (ones-block analytic via T[oc][ey][ex]).  Weights staged in LDS
// (XOR-swizzled rows, pre-swizzled in d_ws by repack), aug in LDS chunk-major.
// A-frag & B-frag both ds_read_b128 -> mfma_f32_32x32x16_bf16 -> direct stores.

#define NB 64
#define NH 64
#define NW 64

typedef __attribute__((ext_vector_type(8)))  short bf16x8;
typedef __attribute__((ext_vector_type(16))) float f32x16;

#define WLDS_BYTES 36864              // 9*32*64*2
#define AUG_BYTES  41472              // 8*324*8*2
#define TL_BYTES   1152               // 288*4
#define SMEM_BYTES (WLDS_BYTES + AUG_BYTES + TL_BYTES)   // 79488

__device__ __forceinline__ float silu(float v) {
    return v / (1.0f + __expf(-v));
}
__device__ __forceinline__ unsigned short tobf(float f) {  // RNE f32->bf16
    unsigned u = __float_as_uint(f);
    u += 0x7FFFu + ((u >> 16) & 1u);
    return (unsigned short)(u >> 16);
}

// ---- per-plane min/max (no atomics) ----
__global__ __launch_bounds__(256) void minmax_kernel(const float* __restrict__ x,
                                                     float* __restrict__ pmm) {
    int plane = blockIdx.x;          // b*64 + ch
    const float4* p = (const float4*)(x + (size_t)plane * 4096);
    int t = threadIdx.x;
    float mn = 3.4e38f, mx = -3.4e38f;
    #pragma unroll
    for (int k = 0; k < 4; ++k) {
        float4 v = p[t + k * 256];
        mn = fminf(mn, fminf(fminf(v.x, v.y), fminf(v.z, v.w)));
        mx = fmaxf(mx, fmaxf(fmaxf(v.x, v.y), fmaxf(v.z, v.w)));
    }
    #pragma unroll
    for (int off = 32; off; off >>= 1) {
        mn = fminf(mn, __shfl_xor(mn, off));
        mx = fmaxf(mx, __shfl_xor(mx, off));
    }
    __shared__ float smn[4], smx[4];
    int wid = t >> 6, lane = t & 63;
    if (lane == 0) { smn[wid] = mn; smx[wid] = mx; }
    __syncthreads();
    if (t == 0) {
        mn = fminf(fminf(smn[0], smn[1]), fminf(smn[2], smn[3]));
        mx = fmaxf(fmaxf(smx[0], smx[1]), fmaxf(smx[2], smx[3]));
        pmm[plane * 2]     = mn;
        pmm[plane * 2 + 1] = mx;
    }
}

// blk 0-3: reduce pmm -> wsf[g]; blk 4-75: repack w -> bf16 swizzled [tap][oc^][k64];
// blk 76: ones-channel analytic table T[oc][ey][ex]
__global__ __launch_bounds__(256) void reduce_repack_kernel(const float* __restrict__ pmm,
                                                            const float* __restrict__ w,
                                                            float* __restrict__ wsf,
                                                            unsigned short* __restrict__ wpk,
                                                            float* __restrict__ Tt) {
    int blk = blockIdx.x;
    int t = threadIdx.x;
    if (blk < 4) {
        int g = blk;
        float mn = 3.4e38f, mx = -3.4e38f;
        #pragma unroll
        for (int j = 0; j < 4; ++j) {
            int p = t + j * 256;             // 0..1023
            int b = p >> 4, c = p & 15;
            int plane = b * 64 + g * 16 + c;
            mn = fminf(mn, pmm[plane * 2]);
            mx = fmaxf(mx, pmm[plane * 2 + 1]);
        }
        #pragma unroll
        for (int off = 32; off; off >>= 1) {
            mn = fminf(mn, __shfl_xor(mn, off));
            mx = fmaxf(mx, __shfl_xor(mx, off));
        }
        __shared__ float smn[4], smx[4];
        int wid = t >> 6, lane = t & 63;
        if (lane == 0) { smn[wid] = mn; smx[wid] = mx; }
        __syncthreads();
        if (t == 0) {
            mn = fminf(fminf(smn[0], smn[1]), fminf(smn[2], smn[3]));
            mx = fmaxf(fmaxf(smx[0], smx[1]), fmaxf(smx[2], smx[3]));
            wsf[g * 2]     = mn;
            wsf[g * 2 + 1] = mx;
        }
    } else if (blk < 76) {
        int idx = (blk - 4) * 256 + t;       // < 18432 = 9*32*64
        int tap = idx / 2048;
        int r = idx - tap * 2048;
        int oc = r >> 6;
        int k = r & 63;
        int orig = (k < 16) ? k : (k + 16);  // skip ones block (orig 16..31)
        // XOR-swizzle rows (16B granules) so LDS A-reads are conflict-light
        int el = tap * 2048 + ((oc * 64 + k) ^ ((oc & 7) << 3));
        wpk[el] = tobf(w[oc * 720 + orig * 9 + tap]);
    } else {
        for (int i = t; i < 288; i += 256) {
            int oc = i / 9, ty = i - oc * 9;
            int ey = ty / 3, ex = ty - ey * 3;
            int ky0 = (ey == 0) ? 1 : 0, ky1 = (ey == 2) ? 1 : 2;
            int kx0 = (ex == 0) ? 1 : 0, kx1 = (ex == 2) ? 1 : 2;
            float s = 0.f;
            for (int c = 0; c < 16; ++c)
                for (int ky = ky0; ky <= ky1; ++ky)
                    for (int kx = kx0; kx <= kx1; ++kx)
                        s += w[oc * 720 + (16 + c) * 9 + ky * 3 + kx];
            Tt[i] = s;
        }
    }
}

__global__ __launch_bounds__(512, 4) void conv_mfma_kernel(const float* __restrict__ x,
                                                           const float* __restrict__ wsf,
                                                           const unsigned short* __restrict__ wpk,
                                                           const float* __restrict__ Tt,
                                                           float* __restrict__ out) {
    extern __shared__ char smem[];
    unsigned short* wl  = (unsigned short*)smem;                    // swizzled weights
    unsigned short* aug = (unsigned short*)(smem + WLDS_BYTES);     // aug[q][pix][8]
    float*          Tl  = (float*)(smem + WLDS_BYTES + AUG_BYTES);  // 288 floats

    // XCD swizzle: consecutive work-chunks of 512 land on one XCD
    int flat = blockIdx.x;                       // 0..4095
    int f = ((flat & 7) << 9) | (flat >> 3);     // bijective
    int tile = f & 15;
    int bg = f >> 4;
    int b = bg & 63;
    int g = bg >> 6;
    int th0 = (tile >> 2) * 16, tw0 = (tile & 3) * 16;

    float xmin = wsf[g * 2];
    float xmax = wsf[g * 2 + 1];
    float inv = 2.0f / (xmax - xmin);

    const float* xg = x + ((size_t)b * 64 + g * 16) * 4096;
    int t = threadIdx.x;

    // ---- weight table: global (pre-swizzled) -> LDS, coalesced uint4 copy ----
    {
        const uint4* src = (const uint4*)wpk;
        uint4* dst = (uint4*)wl;
        #pragma unroll
        for (int i = 0; i < 5; ++i) {
            int idx = t + i * 512;
            if (idx < 2304) dst[idx] = src[idx];
        }
    }
    if (t < 288) Tl[t] = Tt[t];

    // ---- stage augmented tile (all LDS writes are b128) ----
    #pragma unroll
    for (int i = 0; i < 3; ++i) {
        int idx = t + i * 512;
        if (idx < 1296) {
            int kind = idx / 324;                // 0,1: silu ; 2,3: poly
            int pix = idx - kind * 324;
            int ly = pix / 18, lx = pix - ly * 18;
            int gh = th0 + ly - 1, gw = tw0 + lx - 1;
            bool ok = (gh >= 0 && gh < NH && gw >= 0 && gw < NW);
            const float* src = xg + gh * 64 + gw;
            if (kind < 2) {
                int c0 = kind * 8;
                bf16x8 v;
                #pragma unroll
                for (int j = 0; j < 8; ++j) {
                    float val = ok ? src[(size_t)(c0 + j) * 4096] : 0.f;
                    v[j] = (short)tobf(silu(val));
                }
                *(bf16x8*)&aug[(kind * 324 + pix) * 8] = v;
            } else {
                int half = kind & 1;
                int c0 = half * 8;
                bf16x8 v1, v2, v3;
                #pragma unroll
                for (int j = 0; j < 8; ++j) {
                    float val = ok ? src[(size_t)(c0 + j) * 4096] : 0.f;
                    float xn = (val - xmin) * inv - 1.f;
                    float p2 = 1.5f * xn * xn - 0.5f;
                    float p3 = (2.5f * xn * xn - 1.5f) * xn;
                    v1[j] = ok ? (short)tobf(xn) : (short)0;
                    v2[j] = ok ? (short)tobf(p2) : (short)0;
                    v3[j] = ok ? (short)tobf(p3) : (short)0;
                }
                *(bf16x8*)&aug[((2 + half) * 324 + pix) * 8] = v1;
                *(bf16x8*)&aug[((4 + half) * 324 + pix) * 8] = v2;
                *(bf16x8*)&aug[((6 + half) * 324 + pix) * 8] = v3;
            }
        }
    }
    __syncthreads();

    // ---- MFMA: both operands from LDS ----
    int wv = t >> 6;
    int lane = t & 63;
    int lo = lane & 31, hi = lane >> 5;
    int py = 2 * wv + (lo >> 4), px = lo & 15;   // B col = pixel

    // A-frag swizzled element offsets within a tap block (2048 elems)
    int abase[4];
    #pragma unroll
    for (int kcg = 0; kcg < 4; ++kcg)
        abase[kcg] = (lo * 64 + kcg * 16 + hi * 8) ^ ((lo & 7) << 3);

    f32x16 acc = {};
    #pragma unroll
    for (int tap = 0; tap < 9; ++tap) {
        const int ky = tap / 3, kx = tap % 3;
        const int hp = (py + ky) * 18 + (px + kx);
        #pragma unroll
        for (int kcg = 0; kcg < 4; ++kcg) {
            bf16x8 Af = *(const bf16x8*)&wl[tap * 2048 + abase[kcg]];
            bf16x8 Bf = *(const bf16x8*)&aug[(((kcg * 2 + hi) * 324) + hp) * 8];
            acc = __builtin_amdgcn_mfma_f32_32x32x16_bf16(Af, Bf, acc, 0, 0, 0);
        }
    }

    // ---- epilogue: add analytic ones-channel term, direct coalesced stores ----
    int h = th0 + py, wc = tw0 + px;
    int ey = (h == 0) ? 0 : ((h == NH - 1) ? 2 : 1);
    int ex = (wc == 0) ? 0 : ((wc == NW - 1) ? 2 : 1);
    int et = ey * 3 + ex;
    size_t obase = ((size_t)b * 128 + g * 32) * 4096 + (size_t)h * 64 + wc;
    #pragma unroll
    for (int r = 0; r < 16; ++r) {
        int oc = (r & 3) + 8 * (r >> 2) + 4 * hi;
        out[obase + (size_t)oc * 4096] = acc[r] + Tl[oc * 9 + et];
    }
}

__global__ __launch_bounds__(256) void norm_kernel(float* __restrict__ out) {
    int plane = blockIdx.x;      // b*128 + ch
    float4* p = (float4*)(out + (size_t)plane * 4096);
    int t = threadIdx.x;
    float4 v[4];
    float s = 0.f, s2 = 0.f;
    #pragma unroll
    for (int k = 0; k < 4; ++k) {
        v[k] = p[t + k * 256];
        s  += v[k].x + v[k].y + v[k].z + v[k].w;
        s2 += v[k].x * v[k].x + v[k].y * v[k].y + v[k].z * v[k].z + v[k].w * v[k].w;
    }
    #pragma unroll
    for (int off = 32; off; off >>= 1) {
        s  += __shfl_xor(s, off);
        s2 += __shfl_xor(s2, off);
    }
    __shared__ float ss[4], ss2[4];
    int wid = t >> 6, lane = t & 63;
    if (lane == 0) { ss[wid] = s; ss2[wid] = s2; }
    __syncthreads();
    s  = ss[0] + ss[1] + ss[2] + ss[3];
    s2 = ss2[0] + ss2[1] + ss2[2] + ss2[3];
    float mean = s * (1.f / 4096.f);
    float var  = fmaxf(s2 * (1.f / 4096.f) - mean * mean, 0.f);
    float istd = rsqrtf(var + 1e-5f);
    #pragma unroll
    for (int k = 0; k < 4; ++k) {
        float4 o;
        o.x = (v[k].x - mean) * istd; o.x = silu(o.x);
        o.y = (v[k].y - mean) * istd; o.y = silu(o.y);
        o.z = (v[k].z - mean) * istd; o.z = silu(o.z);
        o.w = (v[k].w - mean) * istd; o.w = silu(o.w);
        p[t + k * 256] = o;
    }
}

extern "C" void kernel_launch(void* const* d_in, const int* in_sizes, int n_in,
                              void* d_out, int out_size, void* d_ws, size_t ws_size,
                              hipStream_t stream) {
    const float* x = (const float*)d_in[0];
    const float* w = (const float*)d_in[1];
    float* out = (float*)d_out;
    float* wsf = (float*)d_ws;                                        // 8 floats
    float* pmm = (float*)((char*)d_ws + 64);                          // 8192 floats
    unsigned short* wpk = (unsigned short*)((char*)d_ws + 64 + 32768);// 18432 bf16
    float* Tt = (float*)((char*)d_ws + 64 + 32768 + 36864);           // 288 floats

    static int smem_set = 0;
    if (!smem_set) {
        hipFuncSetAttribute((const void*)conv_mfma_kernel,
                            hipFuncAttributeMaxDynamicSharedMemorySize, SMEM_BYTES);
        smem_set = 1;
    }

    hipLaunchKernelGGL(minmax_kernel, dim3(NB * 64), dim3(256), 0, stream, x, pmm);
    hipLaunchKernelGGL(reduce_repack_kernel, dim3(77), dim3(256), 0, stream, pmm, w, wsf, wpk, Tt);
    hipLaunchKernelGGL(conv_mfma_kernel, dim3(4096), dim3(512), SMEM_BYTES, stream, x, wsf, wpk, Tt, out);
    hipLaunchKernelGGL(norm_kernel, dim3(NB * 128), dim3(256), 0, stream, out);
}

// Round 8
// 148.740 us; speedup vs baseline: 1.5812x; 1.0254x over previous
//
#include <hip/hip_runtime.h>
#include <hip/hip_bf16.h>

// SimpleMetaConvKALN: x (64,64,64,64) f32, w (32,80,3,3) f32 -> out (64,128,64,64) f32
// y = conv3x3(aug(x), w) per group; instance-norm per (b,oc); silu.
// K=64 (ones-block analytic via T[oc][ey][ex]).  Weights staged in LDS
// chunk-major [tap][kq][oc][8] (conflict-free b128 reads, no swizzle),
// aug in LDS chunk-major [q][pix][8].  Native bf16 casts (compiler cvt_pk).

#define NB 64
#define NH 64
#define NW 64

typedef __attribute__((ext_vector_type(8)))  short bf16x8;
typedef __attribute__((ext_vector_type(16))) float f32x16;

#define WLDS_BYTES 36864              // 9*8*32*8*2
#define AUG_BYTES  41472              // 8*324*8*2
#define TL_BYTES   1152               // 288*4
#define SMEM_BYTES (WLDS_BYTES + AUG_BYTES + TL_BYTES)   // 79488

__device__ __forceinline__ float silu(float v) {
    return v / (1.0f + __expf(-v));
}
__device__ __forceinline__ unsigned short tobf(float f) {   // native cvt (RNE)
    union { __hip_bfloat16 h; unsigned short u; } cv;
    cv.h = __float2bfloat16(f);
    return cv.u;
}

// ---- per-plane min/max (no atomics) ----
__global__ __launch_bounds__(256) void minmax_kernel(const float* __restrict__ x,
                                                     float* __restrict__ pmm) {
    int plane = blockIdx.x;          // b*64 + ch
    const float4* p = (const float4*)(x + (size_t)plane * 4096);
    int t = threadIdx.x;
    float mn = 3.4e38f, mx = -3.4e38f;
    #pragma unroll
    for (int k = 0; k < 4; ++k) {
        float4 v = p[t + k * 256];
        mn = fminf(mn, fminf(fminf(v.x, v.y), fminf(v.z, v.w)));
        mx = fmaxf(mx, fmaxf(fmaxf(v.x, v.y), fmaxf(v.z, v.w)));
    }
    #pragma unroll
    for (int off = 32; off; off >>= 1) {
        mn = fminf(mn, __shfl_xor(mn, off));
        mx = fmaxf(mx, __shfl_xor(mx, off));
    }
    __shared__ float smn[4], smx[4];
    int wid = t >> 6, lane = t & 63;
    if (lane == 0) { smn[wid] = mn; smx[wid] = mx; }
    __syncthreads();
    if (t == 0) {
        mn = fminf(fminf(smn[0], smn[1]), fminf(smn[2], smn[3]));
        mx = fmaxf(fmaxf(smx[0], smx[1]), fmaxf(smx[2], smx[3]));
        pmm[plane * 2]     = mn;
        pmm[plane * 2 + 1] = mx;
    }
}

// blk 0-3: reduce pmm -> wsf[g]; blk 4-75: repack w -> bf16 [tap][kq][oc][8];
// blk 76: ones-channel analytic table T[oc][ey][ex]
__global__ __launch_bounds__(256) void reduce_repack_kernel(const float* __restrict__ pmm,
                                                            const float* __restrict__ w,
                                                            float* __restrict__ wsf,
                                                            unsigned short* __restrict__ wpk,
                                                            float* __restrict__ Tt) {
    int blk = blockIdx.x;
    int t = threadIdx.x;
    if (blk < 4) {
        int g = blk;
        float mn = 3.4e38f, mx = -3.4e38f;
        #pragma unroll
        for (int j = 0; j < 4; ++j) {
            int p = t + j * 256;             // 0..1023
            int b = p >> 4, c = p & 15;
            int plane = b * 64 + g * 16 + c;
            mn = fminf(mn, pmm[plane * 2]);
            mx = fmaxf(mx, pmm[plane * 2 + 1]);
        }
        #pragma unroll
        for (int off = 32; off; off >>= 1) {
            mn = fminf(mn, __shfl_xor(mn, off));
            mx = fmaxf(mx, __shfl_xor(mx, off));
        }
        __shared__ float smn[4], smx[4];
        int wid = t >> 6, lane = t & 63;
        if (lane == 0) { smn[wid] = mn; smx[wid] = mx; }
        __syncthreads();
        if (t == 0) {
            mn = fminf(fminf(smn[0], smn[1]), fminf(smn[2], smn[3]));
            mx = fmaxf(fmaxf(smx[0], smx[1]), fmaxf(smx[2], smx[3]));
            wsf[g * 2]     = mn;
            wsf[g * 2 + 1] = mx;
        }
    } else if (blk < 76) {
        int idx = (blk - 4) * 256 + t;       // < 18432 = 9*8*32*8
        int tap = idx / 2048;
        int r   = idx - tap * 2048;
        int kq  = r >> 8;                    // 0..7 (8-wide k chunk)
        int oc  = (r >> 3) & 31;
        int j   = r & 7;
        int k   = kq * 8 + j;
        int orig = (k < 16) ? k : (k + 16);  // skip ones block (orig 16..31)
        wpk[idx] = tobf(w[oc * 720 + orig * 9 + tap]);
    } else {
        for (int i = t; i < 288; i += 256) {
            int oc = i / 9, ty = i - oc * 9;
            int ey = ty / 3, ex = ty - ey * 3;
            int ky0 = (ey == 0) ? 1 : 0, ky1 = (ey == 2) ? 1 : 2;
            int kx0 = (ex == 0) ? 1 : 0, kx1 = (ex == 2) ? 1 : 2;
            float s = 0.f;
            for (int c = 0; c < 16; ++c)
                for (int ky = ky0; ky <= ky1; ++ky)
                    for (int kx = kx0; kx <= kx1; ++kx)
                        s += w[oc * 720 + (16 + c) * 9 + ky * 3 + kx];
            Tt[i] = s;
        }
    }
}

__global__ __launch_bounds__(512, 4) void conv_mfma_kernel(const float* __restrict__ x,
                                                           const float* __restrict__ wsf,
                                                           const unsigned short* __restrict__ wpk,
                                                           const float* __restrict__ Tt,
                                                           float* __restrict__ out) {
    extern __shared__ char smem[];
    unsigned short* wl  = (unsigned short*)smem;                    // [tap][kq][oc][8]
    unsigned short* aug = (unsigned short*)(smem + WLDS_BYTES);     // aug[q][pix][8]
    float*          Tl  = (float*)(smem + WLDS_BYTES + AUG_BYTES);  // 288 floats

    // XCD swizzle: consecutive work-chunks of 512 land on one XCD
    int flat = blockIdx.x;                       // 0..4095
    int f = ((flat & 7) << 9) | (flat >> 3);     // bijective
    int tile = f & 15;
    int bg = f >> 4;
    int b = bg & 63;
    int g = bg >> 6;
    int th0 = (tile >> 2) * 16, tw0 = (tile & 3) * 16;

    float xmin = wsf[g * 2];
    float xmax = wsf[g * 2 + 1];
    float inv = 2.0f / (xmax - xmin);

    const float* xg = x + ((size_t)b * 64 + g * 16) * 4096;
    int t = threadIdx.x;

    // ---- weight table: global -> LDS, coalesced uint4 copy ----
    {
        const uint4* src = (const uint4*)wpk;
        uint4* dst = (uint4*)wl;
        #pragma unroll
        for (int i = 0; i < 5; ++i) {
            int idx = t + i * 512;
            if (idx < 2304) dst[idx] = src[idx];
        }
    }
    if (t < 288) Tl[t] = Tt[t];

    // ---- stage augmented tile (all LDS writes are b128) ----
    #pragma unroll
    for (int i = 0; i < 3; ++i) {
        int idx = t + i * 512;
        if (idx < 1296) {
            int kind = idx / 324;                // 0,1: silu ; 2,3: poly
            int pix = idx - kind * 324;
            int ly = pix / 18, lx = pix - ly * 18;
            int gh = th0 + ly - 1, gw = tw0 + lx - 1;
            bool ok = (gh >= 0 && gh < NH && gw >= 0 && gw < NW);
            const float* src = xg + gh * 64 + gw;
            if (kind < 2) {
                int c0 = kind * 8;
                bf16x8 v;
                #pragma unroll
                for (int j = 0; j < 8; ++j) {
                    float val = ok ? src[(size_t)(c0 + j) * 4096] : 0.f;
                    v[j] = (short)tobf(silu(val));
                }
                *(bf16x8*)&aug[(kind * 324 + pix) * 8] = v;
            } else {
                int half = kind & 1;
                int c0 = half * 8;
                bf16x8 v1, v2, v3;
                #pragma unroll
                for (int j = 0; j < 8; ++j) {
                    float val = ok ? src[(size_t)(c0 + j) * 4096] : 0.f;
                    float xn = (val - xmin) * inv - 1.f;
                    float p2 = 1.5f * xn * xn - 0.5f;
                    float p3 = (2.5f * xn * xn - 1.5f) * xn;
                    v1[j] = ok ? (short)tobf(xn) : (short)0;
                    v2[j] = ok ? (short)tobf(p2) : (short)0;
                    v3[j] = ok ? (short)tobf(p3) : (short)0;
                }
                *(bf16x8*)&aug[((2 + half) * 324 + pix) * 8] = v1;
                *(bf16x8*)&aug[((4 + half) * 324 + pix) * 8] = v2;
                *(bf16x8*)&aug[((6 + half) * 324 + pix) * 8] = v3;
            }
        }
    }
    __syncthreads();

    // ---- MFMA: both operands from LDS, conflict-free b128 reads ----
    int wv = t >> 6;
    int lane = t & 63;
    int lo = lane & 31, hi = lane >> 5;
    int py = 2 * wv + (lo >> 4), px = lo & 15;   // B col = pixel

    f32x16 acc = {};
    #pragma unroll
    for (int tap = 0; tap < 9; ++tap) {
        const int ky = tap / 3, kx = tap % 3;
        const int hp = (py + ky) * 18 + (px + kx);
        #pragma unroll
        for (int kcg = 0; kcg < 4; ++kcg) {
            // A: wl[tap][kq=kcg*2+hi][oc=lo][0..8)
            bf16x8 Af = *(const bf16x8*)&wl[((tap * 8 + kcg * 2 + hi) * 32 + lo) * 8];
            bf16x8 Bf = *(const bf16x8*)&aug[(((kcg * 2 + hi) * 324) + hp) * 8];
            acc = __builtin_amdgcn_mfma_f32_32x32x16_bf16(Af, Bf, acc, 0, 0, 0);
        }
    }

    // ---- epilogue: add analytic ones-channel term, direct coalesced stores ----
    int h = th0 + py, wc = tw0 + px;
    int ey = (h == 0) ? 0 : ((h == NH - 1) ? 2 : 1);
    int ex = (wc == 0) ? 0 : ((wc == NW - 1) ? 2 : 1);
    int et = ey * 3 + ex;
    size_t obase = ((size_t)b * 128 + g * 32) * 4096 + (size_t)h * 64 + wc;
    #pragma unroll
    for (int r = 0; r < 16; ++r) {
        int oc = (r & 3) + 8 * (r >> 2) + 4 * hi;
        out[obase + (size_t)oc * 4096] = acc[r] + Tl[oc * 9 + et];
    }
}

__global__ __launch_bounds__(256) void norm_kernel(float* __restrict__ out) {
    int plane = blockIdx.x;      // b*128 + ch
    float4* p = (float4*)(out + (size_t)plane * 4096);
    int t = threadIdx.x;
    float4 v[4];
    float s = 0.f, s2 = 0.f;
    #pragma unroll
    for (int k = 0; k < 4; ++k) {
        v[k] = p[t + k * 256];
        s  += v[k].x + v[k].y + v[k].z + v[k].w;
        s2 += v[k].x * v[k].x + v[k].y * v[k].y + v[k].z * v[k].z + v[k].w * v[k].w;
    }
    #pragma unroll
    for (int off = 32; off; off >>= 1) {
        s  += __shfl_xor(s, off);
        s2 += __shfl_xor(s2, off);
    }
    __shared__ float ss[4], ss2[4];
    int wid = t >> 6, lane = t & 63;
    if (lane == 0) { ss[wid] = s; ss2[wid] = s2; }
    __syncthreads();
    s  = ss[0] + ss[1] + ss[2] + ss[3];
    s2 = ss2[0] + ss2[1] + ss2[2] + ss2[3];
    float mean = s * (1.f / 4096.f);
    float var  = fmaxf(s2 * (1.f / 4096.f) - mean * mean, 0.f);
    float istd = rsqrtf(var + 1e-5f);
    #pragma unroll
    for (int k = 0; k < 4; ++k) {
        float4 o;
        o.x = (v[k].x - mean) * istd; o.x = silu(o.x);
        o.y = (v[k].y - mean) * istd; o.y = silu(o.y);
        o.z = (v[k].z - mean) * istd; o.z = silu(o.z);
        o.w = (v[k].w - mean) * istd; o.w = silu(o.w);
        p[t + k * 256] = o;
    }
}

extern "C" void kernel_launch(void* const* d_in, const int* in_sizes, int n_in,
                              void* d_out, int out_size, void* d_ws, size_t ws_size,
                              hipStream_t stream) {
    const float* x = (const float*)d_in[0];
    const float* w = (const float*)d_in[1];
    float* out = (float*)d_out;
    float* wsf = (float*)d_ws;                                        // 8 floats
    float* pmm = (float*)((char*)d_ws + 64);                          // 8192 floats
    unsigned short* wpk = (unsigned short*)((char*)d_ws + 64 + 32768);// 18432 bf16
    float* Tt = (float*)((char*)d_ws + 64 + 32768 + 36864);           // 288 floats

    static int smem_set = 0;
    if (!smem_set) {
        hipFuncSetAttribute((const void*)conv_mfma_kernel,
                            hipFuncAttributeMaxDynamicSharedMemorySize, SMEM_BYTES);
        smem_set = 1;
    }

    hipLaunchKernelGGL(minmax_kernel, dim3(NB * 64), dim3(256), 0, stream, x, pmm);
    hipLaunchKernelGGL(reduce_repack_kernel, dim3(77), dim3(256), 0, stream, pmm, w, wsf, wpk, Tt);
    hipLaunchKernelGGL(conv_mfma_kernel, dim3(4096), dim3(512), SMEM_BYTES, stream, x, wsf, wpk, Tt, out);
    hipLaunchKernelGGL(norm_kernel, dim3(NB * 128), dim3(256), 0, stream, out);
}